// Round 19
// baseline (105.499 us; speedup 1.0000x reference)
//
#include <hip/hip_runtime.h>
#include <cstdint>
#include <cmath>

typedef unsigned short u16;
typedef short bf16x8 __attribute__((ext_vector_type(8)));
typedef float f32x4 __attribute__((ext_vector_type(4)));

#define T_DIM 2048
#define B_DIM 16
#define CIN 512
#define COUT 512
#define KIN 1536
#define NROWS (T_DIM * B_DIM)        /* 32768 */
#define UROWS ((T_DIM + 2) * B_DIM)  /* 32800 */

#define NS 48                        /* K-steps of 32 */
#define NWTBLK 192                   /* wt blocks in k_prep */
#define NLOGBLK 8200                 /* logmap blocks (4 rows each) */

#define LOG2E 1.44269504088896f
#define LN2   0.69314718055995f

__device__ __forceinline__ float fast_exp2(float x) {
#if __has_builtin(__builtin_amdgcn_exp2f)
  return __builtin_amdgcn_exp2f(x);
#else
  return __builtin_exp2f(x);
#endif
}
__device__ __forceinline__ float fast_log2(float x) {
#if __has_builtin(__builtin_amdgcn_logf)
  return __builtin_amdgcn_logf(x);   // v_log_f32 = log2(x)
#else
  return __builtin_log2f(x);
#endif
}
__device__ __forceinline__ float fast_rcp(float x) {
  return __builtin_amdgcn_rcpf(x);
}

__device__ __forceinline__ u16 f2bf(float f) {
  unsigned u = __builtin_bit_cast(unsigned, f);
  u = (u + 0x7FFFu + ((u >> 16) & 1u)) >> 16;   // RNE
  return (u16)u;
}

typedef __attribute__((address_space(3))) unsigned int as3u32;
typedef __attribute__((address_space(1))) unsigned int as1u32;

// async global->LDS, 16B per lane; lds must be the wave-uniform base.
__device__ __forceinline__ void gload16(const u16* g, const u16* lds) {
#if __has_builtin(__builtin_amdgcn_global_load_lds)
  __builtin_amdgcn_global_load_lds((as1u32*)(uintptr_t)g,
                                   (as3u32*)(unsigned)(uintptr_t)lds, 16, 0, 0);
#else
  unsigned lane = __lane_id();
  ((uint4*)lds)[lane] = *(const uint4*)g;
#endif
}

// ---- K1: merged prep (2-launch pipeline):
//   blocks [0, NWTBLK): W^T bf16 incl. inline column-norm of wv
//   blocks [NWTBLK, NWTBLK+NLOGBLK): logmap (4 rows per block)
//   block NWTBLK+NLOGBLK: per-channel cosh/sinh(2*bias)
__global__ __launch_bounds__(256) void k_prep(const float* __restrict__ x,
                                              u16* __restrict__ U,
                                              float* __restrict__ nsq,
                                              float beta_ratio,
                                              const float* __restrict__ wv,
                                              const float* __restrict__ bias,
                                              u16* __restrict__ wt,
                                              float* __restrict__ ch,
                                              float* __restrict__ sh) {
  int blk = blockIdx.x;
  if (blk < NWTBLK) {
    __shared__ float tile[64][65];
    __shared__ float part[4][64];
    __shared__ float invl[64];
    int i0 = (blk % 24) * 64;
    int o0 = (blk / 24) * 64;
    int tx = threadIdx.x & 63, ty = threadIdx.x >> 6;
    // inline colnorm: quarter ty sums rows [ty*384, ty*384+384) sequentially
    float s = 0.f;
#pragma unroll 8
    for (int r = ty * 384; r < ty * 384 + 384; ++r) {
      float v = wv[(size_t)r * COUT + o0 + tx];
      s += v * v;
    }
    part[ty][tx] = s;
    for (int r = ty; r < 64; r += 4)
      tile[r][tx] = wv[(size_t)(i0 + r) * COUT + o0 + tx];
    __syncthreads();
    if (threadIdx.x < 64) {
      float t2 = part[0][tx] + part[1][tx] + part[2][tx] + part[3][tx];
      invl[tx] = 1.f / fmaxf(sqrtf(t2), 1e-15f);
    }
    __syncthreads();
    for (int r = ty; r < 64; r += 4) {
      float inv = invl[r];
      wt[(size_t)(o0 + r) * KIN + i0 + tx] = f2bf(tile[tx][r] * inv);
    }
    return;
  }
  if (blk == NWTBLK + NLOGBLK) {
    int o = threadIdx.x;
#pragma unroll
    for (int k = 0; k < 2; ++k, o += 256) {
      float d = 2.f * bias[o];
      float e = fast_exp2(d * LOG2E);
      float ie = fast_rcp(e);
      ch[o] = 0.5f * (e + ie);
      sh[o] = 0.5f * (e - ie);
    }
    return;
  }
  // ---- logmap: one row per wave ----
  int row = (blk - NWTBLK) * 4 + (threadIdx.x >> 6);
  int t = row >> 4;
  int lane = threadIdx.x & 63;
  uint4* urow = (uint4*)(U + (size_t)row * CIN);
  if (t == 0 || t == T_DIM + 1) {
    uint4 z; z.x = z.y = z.z = z.w = 0u;
    urow[lane] = z;
    if (lane == 0) nsq[row] = 0.f;
    return;
  }
  const float4* xr = (const float4*)(x + (size_t)(row - 16) * CIN);
  float4 a = xr[lane * 2];
  float4 b = xr[lane * 2 + 1];
  float s = a.x*a.x + a.y*a.y + a.z*a.z + a.w*a.w
          + b.x*b.x + b.y*b.y + b.z*b.z + b.w*b.w;
#pragma unroll
  for (int d = 1; d < 64; d <<= 1) s += __shfl_xor(s, d);
  float r = sqrtf(s);
  float yn = fmaxf(r, 1e-15f);
  float arg = fminf(yn, 1.0f - 1e-7f);
  float at = 0.5f * LN2 * fast_log2((1.f + arg) * fast_rcp(1.f - arg));
  float f = at / yn * beta_ratio;
  union { u16 h[8]; uint4 v; } pk;
  pk.h[0] = f2bf(a.x * f); pk.h[1] = f2bf(a.y * f);
  pk.h[2] = f2bf(a.z * f); pk.h[3] = f2bf(a.w * f);
  pk.h[4] = f2bf(b.x * f); pk.h[5] = f2bf(b.y * f);
  pk.h[6] = f2bf(b.z * f); pk.h[7] = f2bf(b.w * f);
  urow[lane] = pk.v;
  if (lane == 0) nsq[row] = s * f * f;
}

// ---- K3: fused GEMM + poincare epilogue (r16 exact — best measured) ----
// Block = 128 rows x 512 cols (full output rows -> in-block projection).
// BK=32, 3-deep LDS ring (A 3x8KB + B 3x32KB = 120 KiB), 2-tile lookahead,
// counted vmcnt(5) per tile (never 0 until tail), ONE barrier per tile.
// Incremental addressing; swizzle: phys chunk = c ^ ((row>>1)&3) in 64B
// rows (2-way = free); pre-swizzled global src, linear gload dests.
__global__ __launch_bounds__(512, 2) void k_gemm(const u16* __restrict__ U,
                                                 const u16* __restrict__ WT,
                                                 const float* __restrict__ nsq,
                                                 const float* __restrict__ wg,
                                                 const float* __restrict__ chv,
                                                 const float* __restrict__ shv,
                                                 float* __restrict__ out) {
  __shared__ u16 lA[3][128 * 32];   // 3 x 8 KiB
  __shared__ u16 lB[3][512 * 32];   // 3 x 32 KiB
  int bm = blockIdx.x;              // 256 blocks, 128 rows each
  int tid = threadIdx.x;
  int lane = tid & 63;
  int wid = tid >> 6;
  int wr = wid >> 2, wc = wid & 3;      // wave tile: 64 rows x 128 cols
  int lr = lane & 15;
  int sc = (tid & 3) ^ ((tid >> 3) & 3);            // pre-swizzled src chunk
  int cSwz = ((lane >> 4) ^ ((lr >> 1) & 3)) << 3;  // frag read chunk (u16)
  int ldsOffA = (wr * 64 + lr) * 32 + cSwz;         // loop-invariant
  int ldsOffB = (wc * 128 + lr) * 32 + cSwz;

  f32x4 acc[4][8] = {};

  auto stgA = [&](const u16* g, int p) {
    gload16(g, &lA[p][wid * 512]);
  };
  auto stgB = [&](const u16* g, int p) {
#pragma unroll
    for (int r = 0; r < 4; ++r)
      gload16(g + (size_t)r * (128 * KIN), &lB[p][r * 4096 + wid * 512]);
  };

  // base pointers at t=0 (seg=0, c0=0)
  const u16* gA = U + (size_t)(bm * 128 + (tid >> 2)) * 512 + sc * 8;
  const u16* gB = WT + (size_t)(tid >> 2) * KIN + sc * 8;

  // prologue: stage tiles 0,1
  stgA(gA, 0);      stgB(gB, 0);
  stgA(gA + 32, 1); stgB(gB + 32, 1);
  gA += 64; gB += 64;                                // now at tile 2
  asm volatile("s_waitcnt vmcnt(5)" ::: "memory");   // tile0 landed
  asm volatile("s_barrier" ::: "memory");

  for (int tt = 0; tt < 16; ++tt) {
#pragma unroll
    for (int u = 0; u < 3; ++u) {
      int t = tt * 3 + u;
      int b = u;                        // t % 3
      int p = (u + 2) % 3;
      if (t + 2 < NS) {
        stgA(gA, p); stgB(gB, p);
        int t2 = t + 2;
        gA += ((t2 & 15) == 15) ? 7712 : 32;   // conv-tap seg jump folded
        gB += 32;
      }
      const u16* pA = &lA[b][ldsOffA];
      const u16* pB = &lB[b][ldsOffB];
      bf16x8 af[4], bf[8];
#pragma unroll
      for (int i = 0; i < 4; ++i) af[i] = *(const bf16x8*)(pA + i * 512);
#pragma unroll
      for (int i = 0; i < 8; ++i) bf[i] = *(const bf16x8*)(pB + i * 512);
      __builtin_amdgcn_s_setprio(1);
#pragma unroll
      for (int mi = 0; mi < 4; ++mi)
#pragma unroll
        for (int ni = 0; ni < 8; ++ni)
          acc[mi][ni] = __builtin_amdgcn_mfma_f32_16x16x32_bf16(
              af[mi], bf[ni], acc[mi][ni], 0, 0, 0);
      __builtin_amdgcn_s_setprio(0);
      asm volatile("s_waitcnt lgkmcnt(0)" ::: "memory");  // buf b reads done
      if (t < NS - 2)       asm volatile("s_waitcnt vmcnt(5)" ::: "memory");
      else if (t == NS - 2) asm volatile("s_waitcnt vmcnt(0)" ::: "memory");
      asm volatile("s_barrier" ::: "memory");
    }
  }

  // ---- fused epilogue: all K-loop LDS reads fenced -> reuse lA ----
  float* scr = (float*)&lA[0][0];        // [128][4] wave partials
  float* scl = scr + 128 * 4;            // [128] final scales

  float g8[8], c8[8], s8[8];
#pragma unroll
  for (int ni = 0; ni < 8; ++ni) {
    int col = wc * 128 + ni * 16 + lr;
    g8[ni] = wg[col]; c8[ni] = chv[col]; s8[ni] = shv[col];
  }
  int rbase_loc = wr * 64 + ((lane >> 4) << 2);
  int rbase_glb = bm * 128 + rbase_loc;

#pragma unroll
  for (int mi = 0; mi < 4; ++mi) {
    float r1a[4], r2a[4], ssq[4];
#pragma unroll
    for (int j = 0; j < 4; ++j) {
      int m = rbase_glb + mi * 16 + j;
      float un2 = nsq[m] + nsq[m + 16] + nsq[m + 32];
      float un = sqrtf(un2);
      float unc = fmaxf(un, 1e-15f);
      float e2 = fast_exp2(unc * (2.f * LOG2E));
      float th = (e2 - 1.f) * fast_rcp(e2 + 1.f);
      float sxp = th * fast_rcp(unc);        // expmap0 scale (RC=1)
      float cx2 = sxp * sxp * un2;
      float iden = fast_rcp(fmaxf(1.f - cx2, 1e-15f));
      r1a[j] = 2.f * sxp * iden;
      r2a[j] = (1.f + cx2) * iden;
      ssq[j] = 0.f;
    }
#pragma unroll
    for (int ni = 0; ni < 8; ++ni) {
#pragma unroll
      for (int j = 0; j < 4; ++j) {
        float z = r1a[j] * acc[mi][ni][j] * c8[ni] - r2a[j] * s8[ni];
        float w = z + sqrtf(fmaf(z, z, 1.f));
        float l = fast_log2(w);
        float E = fast_exp2((2.f * g8[ni]) * l);
        float y = 0.5f * (E - fast_rcp(E));
        acc[mi][ni][j] = y;
        ssq[j] += y * y;
      }
    }
#pragma unroll
    for (int j = 0; j < 4; ++j) {
#pragma unroll
      for (int d = 1; d < 16; d <<= 1) ssq[j] += __shfl_xor(ssq[j], d);
    }
    if (lr == 0) {
#pragma unroll
      for (int j = 0; j < 4; ++j)
        scr[(rbase_loc + mi * 16 + j) * 4 + wc] = ssq[j];
    }
  }
  __syncthreads();
  if (tid < 128) {
    float ss = scr[tid * 4] + scr[tid * 4 + 1] + scr[tid * 4 + 2] + scr[tid * 4 + 3];
    float denom = 1.f + sqrtf(1.f + ss);
    float idn = 1.f / denom;
    float nrm = fmaxf(sqrtf(ss) * idn, 1e-15f);
    float maxn = 1.0f - 4e-3f;
    float scale = (nrm > maxn) ? (maxn / nrm) : 1.f;
    scl[tid] = scale * idn;
  }
  __syncthreads();

#pragma unroll
  for (int mi = 0; mi < 4; ++mi) {
    float sc4[4];
#pragma unroll
    for (int j = 0; j < 4; ++j) sc4[j] = scl[rbase_loc + mi * 16 + j];
#pragma unroll
    for (int ni = 0; ni < 8; ++ni) {
      int col = wc * 128 + ni * 16 + lr;
#pragma unroll
      for (int j = 0; j < 4; ++j)
        out[(size_t)(rbase_glb + mi * 16 + j) * COUT + col] = acc[mi][ni][j] * sc4[j];
    }
  }
}

extern "C" void kernel_launch(void* const* d_in, const int* in_sizes, int n_in,
                              void* d_out, int out_size, void* d_ws, size_t ws_size,
                              hipStream_t stream) {
  const float* x    = (const float*)d_in[0];
  const float* wg   = (const float*)d_in[1];
  const float* wv   = (const float*)d_in[2];
  const float* bias = (const float*)d_in[3];
  float* out = (float*)d_out;

  char* ws = (char*)d_ws;
  u16*   U    = (u16*)(ws);                    // 2050*16*512 bf16 = 33,587,200 B
  float* NSQ  = (float*)(ws + 33587200);       // 32800 f32      =    131,200 B
  u16*   WT   = (u16*)(ws + 33718400);         // 512*1536 bf16  =  1,572,864 B
  float* CH   = (float*)(ws + 35291264);       // 512 f32
  float* SH   = (float*)(ws + 35293312);       // 512 f32

  double lb = (lgamma(768.0) + lgamma(0.5) - lgamma(768.5))
            - (lgamma(256.0) + lgamma(0.5) - lgamma(256.5));
  float beta_ratio = (float)exp(lb);           // beta(768,.5)/beta(256,.5)

  k_prep<<<NWTBLK + NLOGBLK + 1, 256, 0, stream>>>(x, U, NSQ, beta_ratio,
                                                   wv, bias, WT, CH, SH);
  k_gemm<<<NROWS / 128, 512, 0, stream>>>(U, WT, NSQ, wg, CH, SH, out);
}

// Round 20
// 96.646 us; speedup vs baseline: 1.0916x; 1.0916x over previous
//
#include <hip/hip_runtime.h>
#include <cstdint>
#include <cmath>

typedef unsigned short u16;
typedef short bf16x8 __attribute__((ext_vector_type(8)));
typedef float f32x4 __attribute__((ext_vector_type(4)));

#define T_DIM 2048
#define B_DIM 16
#define CIN 512
#define COUT 512
#define KIN 1536
#define NROWS (T_DIM * B_DIM)        /* 32768 */
#define UROWS ((T_DIM + 2) * B_DIM)  /* 32800 */

#define NS 48                        /* K-steps of 32 */
#define NWTBLK 192                   /* wt blocks in k_prep */
#define NLOGBLK 8200                 /* logmap blocks (4 rows each) */

#define LOG2E 1.44269504088896f
#define LN2   0.69314718055995f

__device__ __forceinline__ float fast_exp2(float x) {
#if __has_builtin(__builtin_amdgcn_exp2f)
  return __builtin_amdgcn_exp2f(x);
#else
  return __builtin_exp2f(x);
#endif
}
__device__ __forceinline__ float fast_log2(float x) {
#if __has_builtin(__builtin_amdgcn_logf)
  return __builtin_amdgcn_logf(x);   // v_log_f32 = log2(x)
#else
  return __builtin_log2f(x);
#endif
}
__device__ __forceinline__ float fast_rcp(float x) {
  return __builtin_amdgcn_rcpf(x);
}

__device__ __forceinline__ u16 f2bf(float f) {
  unsigned u = __builtin_bit_cast(unsigned, f);
  u = (u + 0x7FFFu + ((u >> 16) & 1u)) >> 16;   // RNE
  return (u16)u;
}

typedef __attribute__((address_space(3))) unsigned int as3u32;
typedef __attribute__((address_space(1))) unsigned int as1u32;

// async global->LDS, 16B per lane; lds must be the wave-uniform base.
__device__ __forceinline__ void gload16(const u16* g, const u16* lds) {
#if __has_builtin(__builtin_amdgcn_global_load_lds)
  __builtin_amdgcn_global_load_lds((as1u32*)(uintptr_t)g,
                                   (as3u32*)(unsigned)(uintptr_t)lds, 16, 0, 0);
#else
  unsigned lane = __lane_id();
  ((uint4*)lds)[lane] = *(const uint4*)g;
#endif
}

// ---- K0: partial column sumsq of weight_v [KIN, COUT] + cosh/sinh(2b) ----
__global__ __launch_bounds__(256) void k_colnorm(const float* __restrict__ wv,
                                                 const float* __restrict__ bias,
                                                 float* __restrict__ partial,
                                                 float* __restrict__ ch,
                                                 float* __restrict__ sh) {
  int o = blockIdx.x * 256 + threadIdx.x;
  int r0 = blockIdx.y * 64;
  float s = 0.f;
#pragma unroll 8
  for (int r = 0; r < 64; ++r) {
    float v = wv[(size_t)(r0 + r) * COUT + o];
    s += v * v;
  }
  partial[(size_t)blockIdx.y * COUT + o] = s;
  if (blockIdx.y == 0) {
    float d = 2.f * bias[o];
    float e = fast_exp2(d * LOG2E);
    float ie = fast_rcp(e);
    ch[o] = 0.5f * (e + ie);
    sh[o] = 0.5f * (e - ie);
  }
}

// ---- K1: merged prep: blocks [0,192) = W^T bf16; rest = logmap ----
__global__ __launch_bounds__(256) void k_prep(const float* __restrict__ x,
                                              u16* __restrict__ U,
                                              float* __restrict__ nsq,
                                              float beta_ratio,
                                              const float* __restrict__ wv,
                                              const float* __restrict__ partial,
                                              u16* __restrict__ wt) {
  int blk = blockIdx.x;
  if (blk < NWTBLK) {
    __shared__ float tile[64][65];
    __shared__ float invl[64];
    int i0 = (blk % 24) * 64;
    int o0 = (blk / 24) * 64;
    int tx = threadIdx.x & 63, ty = threadIdx.x >> 6;
    if (threadIdx.x < 64) {
      float s = 0.f;
#pragma unroll
      for (int j = 0; j < KIN / 64; ++j)
        s += partial[(size_t)j * COUT + o0 + threadIdx.x];
      invl[threadIdx.x] = 1.f / fmaxf(sqrtf(s), 1e-15f);
    }
    for (int r = ty; r < 64; r += 4)
      tile[r][tx] = wv[(size_t)(i0 + r) * COUT + o0 + tx];
    __syncthreads();
    for (int r = ty; r < 64; r += 4) {
      float inv = invl[r];
      wt[(size_t)(o0 + r) * KIN + i0 + tx] = f2bf(tile[tx][r] * inv);
    }
    return;
  }
  // ---- logmap: one row per wave ----
  int row = (blk - NWTBLK) * 4 + (threadIdx.x >> 6);
  int t = row >> 4;
  int lane = threadIdx.x & 63;
  uint4* urow = (uint4*)(U + (size_t)row * CIN);
  if (t == 0 || t == T_DIM + 1) {
    uint4 z; z.x = z.y = z.z = z.w = 0u;
    urow[lane] = z;
    if (lane == 0) nsq[row] = 0.f;
    return;
  }
  const float4* xr = (const float4*)(x + (size_t)(row - 16) * CIN);
  float4 a = xr[lane * 2];
  float4 b = xr[lane * 2 + 1];
  float s = a.x*a.x + a.y*a.y + a.z*a.z + a.w*a.w
          + b.x*b.x + b.y*b.y + b.z*b.z + b.w*b.w;
#pragma unroll
  for (int d = 1; d < 64; d <<= 1) s += __shfl_xor(s, d);
  float r = sqrtf(s);
  float yn = fmaxf(r, 1e-15f);
  float arg = fminf(yn, 1.0f - 1e-7f);
  float at = 0.5f * LN2 * fast_log2((1.f + arg) * fast_rcp(1.f - arg));
  float f = at / yn * beta_ratio;
  union { u16 h[8]; uint4 v; } pk;
  pk.h[0] = f2bf(a.x * f); pk.h[1] = f2bf(a.y * f);
  pk.h[2] = f2bf(a.z * f); pk.h[3] = f2bf(a.w * f);
  pk.h[4] = f2bf(b.x * f); pk.h[5] = f2bf(b.y * f);
  pk.h[6] = f2bf(b.z * f); pk.h[7] = f2bf(b.w * f);
  urow[lane] = pk.v;
  if (lane == 0) nsq[row] = s * f * f;
}

// ---- K3: fused GEMM + poincare epilogue (r16 exact — best measured) ----
// Block = 128 rows x 512 cols (full output rows -> in-block projection).
// BK=32, 3-deep LDS ring (A 3x8KB + B 3x32KB = 120 KiB), 2-tile lookahead,
// counted vmcnt(5) per tile (never 0 until tail), ONE barrier per tile.
// Incremental addressing; swizzle: phys chunk = c ^ ((row>>1)&3) in 64B
// rows (2-way = free); pre-swizzled global src, linear gload dests.
__global__ __launch_bounds__(512, 2) void k_gemm(const u16* __restrict__ U,
                                                 const u16* __restrict__ WT,
                                                 const float* __restrict__ nsq,
                                                 const float* __restrict__ wg,
                                                 const float* __restrict__ chv,
                                                 const float* __restrict__ shv,
                                                 float* __restrict__ out) {
  __shared__ u16 lA[3][128 * 32];   // 3 x 8 KiB
  __shared__ u16 lB[3][512 * 32];   // 3 x 32 KiB
  int bm = blockIdx.x;              // 256 blocks, 128 rows each
  int tid = threadIdx.x;
  int lane = tid & 63;
  int wid = tid >> 6;
  int wr = wid >> 2, wc = wid & 3;      // wave tile: 64 rows x 128 cols
  int lr = lane & 15;
  int sc = (tid & 3) ^ ((tid >> 3) & 3);            // pre-swizzled src chunk
  int cSwz = ((lane >> 4) ^ ((lr >> 1) & 3)) << 3;  // frag read chunk (u16)
  int ldsOffA = (wr * 64 + lr) * 32 + cSwz;         // loop-invariant
  int ldsOffB = (wc * 128 + lr) * 32 + cSwz;

  f32x4 acc[4][8] = {};

  auto stgA = [&](const u16* g, int p) {
    gload16(g, &lA[p][wid * 512]);
  };
  auto stgB = [&](const u16* g, int p) {
#pragma unroll
    for (int r = 0; r < 4; ++r)
      gload16(g + (size_t)r * (128 * KIN), &lB[p][r * 4096 + wid * 512]);
  };

  // base pointers at t=0 (seg=0, c0=0)
  const u16* gA = U + (size_t)(bm * 128 + (tid >> 2)) * 512 + sc * 8;
  const u16* gB = WT + (size_t)(tid >> 2) * KIN + sc * 8;

  // prologue: stage tiles 0,1
  stgA(gA, 0);      stgB(gB, 0);
  stgA(gA + 32, 1); stgB(gB + 32, 1);
  gA += 64; gB += 64;                                // now at tile 2
  asm volatile("s_waitcnt vmcnt(5)" ::: "memory");   // tile0 landed
  asm volatile("s_barrier" ::: "memory");

  for (int tt = 0; tt < 16; ++tt) {
#pragma unroll
    for (int u = 0; u < 3; ++u) {
      int t = tt * 3 + u;
      int b = u;                        // t % 3
      int p = (u + 2) % 3;
      if (t + 2 < NS) {
        stgA(gA, p); stgB(gB, p);
        int t2 = t + 2;
        gA += ((t2 & 15) == 15) ? 7712 : 32;   // conv-tap seg jump folded
        gB += 32;
      }
      const u16* pA = &lA[b][ldsOffA];
      const u16* pB = &lB[b][ldsOffB];
      bf16x8 af[4], bf[8];
#pragma unroll
      for (int i = 0; i < 4; ++i) af[i] = *(const bf16x8*)(pA + i * 512);
#pragma unroll
      for (int i = 0; i < 8; ++i) bf[i] = *(const bf16x8*)(pB + i * 512);
      __builtin_amdgcn_s_setprio(1);
#pragma unroll
      for (int mi = 0; mi < 4; ++mi)
#pragma unroll
        for (int ni = 0; ni < 8; ++ni)
          acc[mi][ni] = __builtin_amdgcn_mfma_f32_16x16x32_bf16(
              af[mi], bf[ni], acc[mi][ni], 0, 0, 0);
      __builtin_amdgcn_s_setprio(0);
      asm volatile("s_waitcnt lgkmcnt(0)" ::: "memory");  // buf b reads done
      if (t < NS - 2)       asm volatile("s_waitcnt vmcnt(5)" ::: "memory");
      else if (t == NS - 2) asm volatile("s_waitcnt vmcnt(0)" ::: "memory");
      asm volatile("s_barrier" ::: "memory");
    }
  }

  // ---- fused epilogue: all K-loop LDS reads fenced -> reuse lA ----
  float* scr = (float*)&lA[0][0];        // [128][4] wave partials
  float* scl = scr + 128 * 4;            // [128] final scales

  float g8[8], c8[8], s8[8];
#pragma unroll
  for (int ni = 0; ni < 8; ++ni) {
    int col = wc * 128 + ni * 16 + lr;
    g8[ni] = wg[col]; c8[ni] = chv[col]; s8[ni] = shv[col];
  }
  int rbase_loc = wr * 64 + ((lane >> 4) << 2);
  int rbase_glb = bm * 128 + rbase_loc;

#pragma unroll
  for (int mi = 0; mi < 4; ++mi) {
    float r1a[4], r2a[4], ssq[4];
#pragma unroll
    for (int j = 0; j < 4; ++j) {
      int m = rbase_glb + mi * 16 + j;
      float un2 = nsq[m] + nsq[m + 16] + nsq[m + 32];
      float un = sqrtf(un2);
      float unc = fmaxf(un, 1e-15f);
      float e2 = fast_exp2(unc * (2.f * LOG2E));
      float th = (e2 - 1.f) * fast_rcp(e2 + 1.f);
      float sxp = th * fast_rcp(unc);        // expmap0 scale (RC=1)
      float cx2 = sxp * sxp * un2;
      float iden = fast_rcp(fmaxf(1.f - cx2, 1e-15f));
      r1a[j] = 2.f * sxp * iden;
      r2a[j] = (1.f + cx2) * iden;
      ssq[j] = 0.f;
    }
#pragma unroll
    for (int ni = 0; ni < 8; ++ni) {
#pragma unroll
      for (int j = 0; j < 4; ++j) {
        float z = r1a[j] * acc[mi][ni][j] * c8[ni] - r2a[j] * s8[ni];
        float w = z + sqrtf(fmaf(z, z, 1.f));
        float l = fast_log2(w);
        float E = fast_exp2((2.f * g8[ni]) * l);
        float y = 0.5f * (E - fast_rcp(E));
        acc[mi][ni][j] = y;
        ssq[j] += y * y;
      }
    }
#pragma unroll
    for (int j = 0; j < 4; ++j) {
#pragma unroll
      for (int d = 1; d < 16; d <<= 1) ssq[j] += __shfl_xor(ssq[j], d);
    }
    if (lr == 0) {
#pragma unroll
      for (int j = 0; j < 4; ++j)
        scr[(rbase_loc + mi * 16 + j) * 4 + wc] = ssq[j];
    }
  }
  __syncthreads();
  if (tid < 128) {
    float ss = scr[tid * 4] + scr[tid * 4 + 1] + scr[tid * 4 + 2] + scr[tid * 4 + 3];
    float denom = 1.f + sqrtf(1.f + ss);
    float idn = 1.f / denom;
    float nrm = fmaxf(sqrtf(ss) * idn, 1e-15f);
    float maxn = 1.0f - 4e-3f;
    float scale = (nrm > maxn) ? (maxn / nrm) : 1.f;
    scl[tid] = scale * idn;
  }
  __syncthreads();

#pragma unroll
  for (int mi = 0; mi < 4; ++mi) {
    float sc4[4];
#pragma unroll
    for (int j = 0; j < 4; ++j) sc4[j] = scl[rbase_loc + mi * 16 + j];
#pragma unroll
    for (int ni = 0; ni < 8; ++ni) {
      int col = wc * 128 + ni * 16 + lr;
#pragma unroll
      for (int j = 0; j < 4; ++j)
        out[(size_t)(rbase_glb + mi * 16 + j) * COUT + col] = acc[mi][ni][j] * sc4[j];
    }
  }
}

extern "C" void kernel_launch(void* const* d_in, const int* in_sizes, int n_in,
                              void* d_out, int out_size, void* d_ws, size_t ws_size,
                              hipStream_t stream) {
  const float* x    = (const float*)d_in[0];
  const float* wg   = (const float*)d_in[1];
  const float* wv   = (const float*)d_in[2];
  const float* bias = (const float*)d_in[3];
  float* out = (float*)d_out;

  char* ws = (char*)d_ws;
  u16*   U    = (u16*)(ws);                    // 2050*16*512 bf16 = 33,587,200 B
  float* NSQ  = (float*)(ws + 33587200);       // 32800 f32      =    131,200 B
  u16*   WT   = (u16*)(ws + 33718400);         // 512*1536 bf16  =  1,572,864 B
  float* CH   = (float*)(ws + 35291264);       // 512 f32
  float* SH   = (float*)(ws + 35293312);       // 512 f32
  float* PART = (float*)(ws + 35295360);       // 24*512 f32 = 49,152 B

  double lb = (lgamma(768.0) + lgamma(0.5) - lgamma(768.5))
            - (lgamma(256.0) + lgamma(0.5) - lgamma(256.5));
  float beta_ratio = (float)exp(lb);           // beta(768,.5)/beta(256,.5)

  k_colnorm<<<dim3(COUT / 256, KIN / 64), 256, 0, stream>>>(wv, bias, PART, CH, SH);
  k_prep<<<NWTBLK + NLOGBLK, 256, 0, stream>>>(x, U, NSQ, beta_ratio, wv, PART, WT);
  k_gemm<<<NROWS / 128, 512, 0, stream>>>(U, WT, NSQ, wg, CH, SH, out);
}